// Round 3
// baseline (348.315 us; speedup 1.0000x reference)
//
#include <hip/hip_runtime.h>
#include <stdint.h>

#define M_TOK 256
#define K_IN  4096
#define N_OUT 11008
#define K_EXT 4160              // 4096 + 16 lora + 48 zero pad
#define ROWB  (K_EXT * 2)       // bytes per x_ext row = 8320
#define BM    256               // all tokens -> qweight read exactly once
#define BN    32
#define NBLK  344               // 11008 / 32
#define STEPS 65                // 64 qweight steps + 1 lora tail step

typedef __attribute__((ext_vector_type(8))) short s16x8;
typedef __attribute__((ext_vector_type(8))) unsigned short u16x8;
typedef __attribute__((ext_vector_type(4))) float f32x4;

__device__ __forceinline__ unsigned short f2bf(float f) {
  union { float f; unsigned int u; } v; v.f = f;
  unsigned int u = v.u;
  u += 0x7fffu + ((u >> 16) & 1u);   // round-to-nearest-even
  return (unsigned short)(u >> 16);
}

// ---- prep: x fp32 -> bf16 row (stride K_EXT) + lora t2 appended as cols 4096.. ----
__global__ __launch_bounds__(512) void prep_kernel(
    const float* __restrict__ x, const float* __restrict__ la,
    unsigned short* __restrict__ xe)
{
  const int m   = blockIdx.x;
  const int tid = threadIdx.x;         // 512 threads, 8 floats each
  const int k   = tid * 8;
  const float* xr = x + (size_t)m * K_IN;
  const float4 f0 = *(const float4*)(xr + k);
  const float4 f1 = *(const float4*)(xr + k + 4);
  u16x8 o;
  o[0] = f2bf(f0.x); o[1] = f2bf(f0.y); o[2] = f2bf(f0.z); o[3] = f2bf(f0.w);
  o[4] = f2bf(f1.x); o[5] = f2bf(f1.y); o[6] = f2bf(f1.z); o[7] = f2bf(f1.w);
  *(u16x8*)(xe + (size_t)m * K_EXT + k) = o;

  float acc[16];
  #pragma unroll
  for (int r = 0; r < 16; ++r) {
    const float4 a0 = *(const float4*)(la + r * K_IN + k);
    const float4 a1 = *(const float4*)(la + r * K_IN + k + 4);
    acc[r] = f0.x * a0.x + f0.y * a0.y + f0.z * a0.z + f0.w * a0.w
           + f1.x * a1.x + f1.y * a1.y + f1.z * a1.z + f1.w * a1.w;
  }
  #pragma unroll
  for (int r = 0; r < 16; ++r) {
    #pragma unroll
    for (int off = 32; off > 0; off >>= 1) acc[r] += __shfl_down(acc[r], off);
  }
  __shared__ float red[8][16];
  const int wave = tid >> 6, lane = tid & 63;
  if (lane == 0) {
    #pragma unroll
    for (int r = 0; r < 16; ++r) red[wave][r] = acc[r];
  }
  __syncthreads();
  if (tid < 16) {
    float s = 0.f;
    #pragma unroll
    for (int w = 0; w < 8; ++w) s += red[w][tid];
    xe[(size_t)m * K_EXT + K_IN + tid] = f2bf(2.0f * s);   // SCALING folded
  } else if (tid < 64) {
    xe[(size_t)m * K_EXT + K_IN + tid] = 0;                // zero pad (ws poisoned)
  }
}

// ---------------- main: 256 x 11008 GEMM, dequant-on-the-fly ----------------
// BM=256 x BN=32, BK=64, 512 threads (8 waves, each 32x32 tile), double-buffered.
__global__ __launch_bounds__(512, 4) void gptq_lora_gemm(
    const int* __restrict__ qw, const float* __restrict__ sc,
    const int* __restrict__ zr, const float* __restrict__ lb,
    const unsigned short* __restrict__ xe, float* __restrict__ out)
{
  __shared__ unsigned short xs[2][BM * 64];   // 2 x 32 KB, XOR-swizzled rows
  __shared__ unsigned short wt[2][BN * 64];   // 2 x  4 KB, XOR-swizzled rows

  const int tid  = threadIdx.x;
  const int wave = tid >> 6;      // 0..7 -> 32 M-rows each
  const int lane = tid & 63;
  const int n0   = blockIdx.x * BN;

  // W-staging: row = tid>>4 (0..31), 4 ints at (tid&15)*4
  const int srow  = tid >> 4;
  const int sko   = (tid & 15) * 4;
  const int nglob = n0 + srow;
  const size_t qrow = (size_t)nglob * K_IN;
  const int wt_off  = srow * 128 + ((sko * 2) ^ ((srow & 7) << 4));
  const bool lora_ld = (sko < 16);

  f32x4 acc[2][2];
  #pragma unroll
  for (int i = 0; i < 2; ++i)
    #pragma unroll
    for (int j = 0; j < 2; ++j) acc[i][j] = (f32x4)0.f;

  const int arow_lo = lane & 15;
  const int kb_hi   = (lane >> 4) * 16;

  const char* xb = (const char*)xe;

  auto stage_x = [&](int buf, int step) {
    const int k0 = step * 64;
    #pragma unroll
    for (int i = 0; i < 4; ++i) {
      const int base = (wave * 32 + i * 8) * 128;          // wave-uniform LDS byte base
      const int o    = base + lane * 16;
      const int mrow = o >> 7;
      const int kb   = o & 127;
      const char* src = xb + (size_t)mrow * ROWB + k0 * 2 + (kb ^ ((mrow & 7) << 4));
      __builtin_amdgcn_global_load_lds(
          (const __attribute__((address_space(1))) void*)src,
          (__attribute__((address_space(3))) void*)((char*)xs[buf] + base),
          16, 0, 0);
    }
  };

  auto load_q = [&](int step, int4& q, float& s, float& z) {
    if (step < 64) {
      const int g = step >> 1;                 // GROUP_SIZE=128 = 2 k-steps
      s = sc[nglob * 32 + g];
      z = (float)zr[nglob * 32 + g];
      q = *(const int4*)(qw + qrow + step * 64 + sko);
    } else if (lora_ld) {
      q = *(const int4*)(lb + (size_t)nglob * 16 + sko);
    }
  };

  auto dequant_write = [&](int step, const int4& q, float s, float z, int buf) {
    unsigned short wv[4];
    if (step < 64) {
      wv[0] = f2bf(((float)q.x - z) * s);
      wv[1] = f2bf(((float)q.y - z) * s);
      wv[2] = f2bf(((float)q.z - z) * s);
      wv[3] = f2bf(((float)q.w - z) * s);
    } else {
      wv[0] = lora_ld ? f2bf(__int_as_float(q.x)) : (unsigned short)0;
      wv[1] = lora_ld ? f2bf(__int_as_float(q.y)) : (unsigned short)0;
      wv[2] = lora_ld ? f2bf(__int_as_float(q.z)) : (unsigned short)0;
      wv[3] = lora_ld ? f2bf(__int_as_float(q.w)) : (unsigned short)0;
    }
    int2 pk;
    pk.x = (int)wv[0] | ((int)wv[1] << 16);
    pk.y = (int)wv[2] | ((int)wv[3] << 16);
    *(int2*)((char*)wt[buf] + wt_off) = pk;
  };

  auto compute = [&](int buf) {
    s16x8 bfr[2][2];
    #pragma unroll
    for (int nf = 0; nf < 2; ++nf) {
      const int c   = nf * 16 + arow_lo;
      const int swz = (c & 7) << 4;
      #pragma unroll
      for (int ks = 0; ks < 2; ++ks) {
        const int off = c * 128 + ((ks * 64 + kb_hi) ^ swz);
        bfr[nf][ks] = *(const s16x8*)((const char*)wt[buf] + off);
      }
    }
    #pragma unroll
    for (int mf = 0; mf < 2; ++mf) {
      const int r   = wave * 32 + mf * 16 + arow_lo;
      const int swz = (r & 7) << 4;
      s16x8 af[2];
      #pragma unroll
      for (int ks = 0; ks < 2; ++ks) {
        const int off = r * 128 + ((ks * 64 + kb_hi) ^ swz);
        af[ks] = *(const s16x8*)((const char*)xs[buf] + off);
      }
      #pragma unroll
      for (int nf = 0; nf < 2; ++nf) {
        acc[mf][nf] = __builtin_amdgcn_mfma_f32_16x16x32_bf16(af[0], bfr[nf][0], acc[mf][nf], 0, 0, 0);
        acc[mf][nf] = __builtin_amdgcn_mfma_f32_16x16x32_bf16(af[1], bfr[nf][1], acc[mf][nf], 0, 0, 0);
      }
    }
  };

  // ---- prologue ----
  {
    int4 q; float s = 0.f, z = 0.f;
    load_q(0, q, s, z);
    stage_x(0, 0);
    dequant_write(0, q, s, z, 0);
  }
  __syncthreads();

  // ---- 2-phase pipelined main loop ----
  int buf = 0;
  #pragma unroll 1
  for (int t = 0; t < STEPS; ++t) {
    const bool more = (t + 1 < STEPS);
    int4 qn; float sn = 0.f, zn = 0.f;
    if (more) {
      load_q(t + 1, qn, sn, zn);     // global -> regs (1 dwordx4)
      stage_x(buf ^ 1, t + 1);       // global -> LDS (async)
    }
    compute(buf);                    // 8 MFMA on current buffer
    if (more) dequant_write(t + 1, qn, sn, zn, buf ^ 1);
    __syncthreads();
    buf ^= 1;
  }

  // ---- epilogue: C/D layout col=lane&15, row=(lane>>4)*4+reg ----
  const int rb = wave * 32 + (lane >> 4) * 4;
  const int cb = n0 + (lane & 15);
  #pragma unroll
  for (int mf = 0; mf < 2; ++mf) {
    #pragma unroll
    for (int nf = 0; nf < 2; ++nf) {
      #pragma unroll
      for (int j = 0; j < 4; ++j) {
        out[(size_t)(rb + mf * 16 + j) * N_OUT + (cb + nf * 16)] = acc[mf][nf][j];
      }
    }
  }
}

extern "C" void kernel_launch(void* const* d_in, const int* in_sizes, int n_in,
                              void* d_out, int out_size, void* d_ws, size_t ws_size,
                              hipStream_t stream) {
  const float* x  = (const float*)d_in[0];
  const int*   qw = (const int*)d_in[1];
  const float* sc = (const float*)d_in[2];
  const int*   zr = (const int*)d_in[3];
  const float* la = (const float*)d_in[4];
  const float* lb = (const float*)d_in[5];
  float* out = (float*)d_out;
  unsigned short* xe = (unsigned short*)d_ws;   // 256*4160*2 = 2.03 MB

  prep_kernel<<<M_TOK, 512, 0, stream>>>(x, la, xe);
  gptq_lora_gemm<<<NBLK, 512, 0, stream>>>(qw, sc, zr, lb, xe, out);
}

// Round 4
// 321.195 us; speedup vs baseline: 1.0844x; 1.0844x over previous
//
#include <hip/hip_runtime.h>
#include <stdint.h>

#define M_TOK 256
#define K_IN  4096
#define N_OUT 11008
#define K_EXT 4160              // 4096 + 16 lora + 48 zero pad
#define ROWB  (K_EXT * 2)       // bytes per x_ext row = 8320
#define BM    256               // all tokens -> qweight read exactly once
#define BN    32
#define NBLK  344               // 11008 / 32

typedef __attribute__((ext_vector_type(8))) short s16x8;
typedef __attribute__((ext_vector_type(8))) unsigned short u16x8;
typedef __attribute__((ext_vector_type(4))) float f32x4;

#define ASM_VMCNT_10() asm volatile("s_waitcnt vmcnt(10)" ::: "memory")
#define ASM_VMCNT_7()  asm volatile("s_waitcnt vmcnt(7)"  ::: "memory")
#define ASM_VMCNT_5()  asm volatile("s_waitcnt vmcnt(5)"  ::: "memory")
#define ASM_VMCNT_0()  asm volatile("s_waitcnt vmcnt(0)"  ::: "memory")
#define ASM_LGKM_0()   asm volatile("s_waitcnt lgkmcnt(0)" ::: "memory")
#define SBAR()         __builtin_amdgcn_s_barrier()
#define SCHED0()       __builtin_amdgcn_sched_barrier(0)

__device__ __forceinline__ unsigned short f2bf(float f) {
  union { float f; unsigned int u; } v; v.f = f;
  unsigned int u = v.u;
  u += 0x7fffu + ((u >> 16) & 1u);   // round-to-nearest-even
  return (unsigned short)(u >> 16);
}

// ---- prep: x fp32 -> bf16 row (stride K_EXT) + lora t2 appended as cols 4096.. ----
// one block per token row m; low register pressure (2 accs/wave).
__global__ __launch_bounds__(512) void prep_kernel(
    const float* __restrict__ x, const float* __restrict__ la,
    unsigned short* __restrict__ xe)
{
  const int m   = blockIdx.x;
  const int tid = threadIdx.x;
  const int k   = tid * 8;
  const float* xr = x + (size_t)m * K_IN;
  unsigned short* xer = xe + (size_t)m * K_EXT;

  const float4 f0 = *(const float4*)(xr + k);
  const float4 f1 = *(const float4*)(xr + k + 4);
  u16x8 o;
  o[0] = f2bf(f0.x); o[1] = f2bf(f0.y); o[2] = f2bf(f0.z); o[3] = f2bf(f0.w);
  o[4] = f2bf(f1.x); o[5] = f2bf(f1.y); o[6] = f2bf(f1.z); o[7] = f2bf(f1.w);
  *(u16x8*)(xer + k) = o;

  if (tid >= 464) xer[K_IN + 16 + (tid - 464)] = 0;   // zero pad cols 4112..4159

  // lora: wave w owns r = 2w, 2w+1
  const int wave = tid >> 6, lane = tid & 63;
  const float* a0p = la + (size_t)(wave * 2) * K_IN;
  const float* a1p = a0p + K_IN;
  float s0 = 0.f, s1 = 0.f;
  #pragma unroll 4
  for (int it = 0; it < 16; ++it) {
    const int kk = it * 256 + lane * 4;
    const float4 xv = *(const float4*)(xr + kk);
    const float4 a0 = *(const float4*)(a0p + kk);
    const float4 a1 = *(const float4*)(a1p + kk);
    s0 += xv.x * a0.x + xv.y * a0.y + xv.z * a0.z + xv.w * a0.w;
    s1 += xv.x * a1.x + xv.y * a1.y + xv.z * a1.z + xv.w * a1.w;
  }
  #pragma unroll
  for (int off = 32; off > 0; off >>= 1) {
    s0 += __shfl_down(s0, off);
    s1 += __shfl_down(s1, off);
  }
  if (lane == 0) {
    xer[K_IN + wave * 2]     = f2bf(2.0f * s0);   // SCALING folded
    xer[K_IN + wave * 2 + 1] = f2bf(2.0f * s1);
  }
}

// ---------------- main: 256 x 11008 GEMM, dequant-on-the-fly ----------------
// BM=256 x BN=32, BK=64, 512 threads (8 waves x 32 M-rows), raw-barrier
// pipeline with counted vmcnt: x staged depth-1 (wave-private rows!),
// qweight prefetched depth-2. One s_barrier per step (wt visibility only).
__global__ __launch_bounds__(512, 4) void gptq_lora_gemm(
    const int* __restrict__ qw, const float* __restrict__ sc,
    const int* __restrict__ zr, const float* __restrict__ lb,
    const unsigned short* __restrict__ xe, float* __restrict__ out)
{
  __shared__ unsigned short xs[2][BM * 64];   // 2 x 32 KB, XOR-swizzled rows
  __shared__ unsigned short wt[2][BN * 64];   // 2 x  4 KB, XOR-swizzled rows

  const int tid  = threadIdx.x;
  const int wave = tid >> 6;      // 0..7 -> 32 M-rows each (stage & read own rows)
  const int lane = tid & 63;
  const int n0   = blockIdx.x * BN;

  // W-staging: row = tid>>4 (0..31), 4 ints at (tid&15)*4
  const int srow  = tid >> 4;
  const int sko   = (tid & 15) * 4;
  const int nglob = n0 + srow;
  const size_t qrow = (size_t)nglob * K_IN;
  const int wt_off  = srow * 128 + ((sko * 2) ^ ((srow & 7) << 4));
  const bool lora_ld = (sko < 16);

  f32x4 acc[2][2];
  #pragma unroll
  for (int i = 0; i < 2; ++i)
    #pragma unroll
    for (int j = 0; j < 2; ++j) acc[i][j] = (f32x4)0.f;

  const int arow_lo = lane & 15;
  const int kb_hi   = (lane >> 4) * 16;
  const char* xb = (const char*)xe;

  auto stage_x = [&](int buf, int step) {
    const int k0b = step * 128;                          // byte offset in row
    #pragma unroll
    for (int i = 0; i < 4; ++i) {
      const int base = (wave * 32 + i * 8) * 128;        // wave-uniform LDS base
      const int o    = base + lane * 16;
      const int mrow = o >> 7;
      const int kb   = o & 127;
      const char* src = xb + (size_t)mrow * ROWB + k0b + (kb ^ ((mrow & 7) << 4));
      __builtin_amdgcn_global_load_lds(
          (const __attribute__((address_space(1))) void*)src,
          (__attribute__((address_space(3))) void*)((char*)xs[buf] + base),
          16, 0, 0);
    }
  };

  auto load_q = [&](int step, int4& q, float& s, float& z) {
    const int g = step >> 1;                 // GROUP_SIZE=128 = 2 k-steps
    s = sc[nglob * 32 + g];
    z = (float)zr[nglob * 32 + g];
    q = *(const int4*)(qw + qrow + step * 64 + sko);
  };

  auto dequant_write = [&](const int4& q, float s, float z, int buf) {
    unsigned short wv0 = f2bf(((float)q.x - z) * s);
    unsigned short wv1 = f2bf(((float)q.y - z) * s);
    unsigned short wv2 = f2bf(((float)q.z - z) * s);
    unsigned short wv3 = f2bf(((float)q.w - z) * s);
    int2 pk;
    pk.x = (int)wv0 | ((int)wv1 << 16);
    pk.y = (int)wv2 | ((int)wv3 << 16);
    *(int2*)((char*)wt[buf] + wt_off) = pk;
  };

  auto compute = [&](int buf) {
    s16x8 bfr[2][2];
    #pragma unroll
    for (int nf = 0; nf < 2; ++nf) {
      const int c   = nf * 16 + arow_lo;
      const int swz = (c & 7) << 4;
      #pragma unroll
      for (int ks = 0; ks < 2; ++ks) {
        const int off = c * 128 + ((ks * 64 + kb_hi) ^ swz);
        bfr[nf][ks] = *(const s16x8*)((const char*)wt[buf] + off);
      }
    }
    #pragma unroll
    for (int mf = 0; mf < 2; ++mf) {
      const int r   = wave * 32 + mf * 16 + arow_lo;
      const int swz = (r & 7) << 4;
      s16x8 af[2];
      #pragma unroll
      for (int ks = 0; ks < 2; ++ks) {
        const int off = r * 128 + ((ks * 64 + kb_hi) ^ swz);
        af[ks] = *(const s16x8*)((const char*)xs[buf] + off);
      }
      #pragma unroll
      for (int nf = 0; nf < 2; ++nf) {
        acc[mf][nf] = __builtin_amdgcn_mfma_f32_16x16x32_bf16(af[0], bfr[nf][0], acc[mf][nf], 0, 0, 0);
        acc[mf][nf] = __builtin_amdgcn_mfma_f32_16x16x32_bf16(af[1], bfr[nf][1], acc[mf][nf], 0, 0, 0);
      }
    }
  };

  // ---- prologue: q(0), x(0), q(1); wt[0] filled ----
  int4 qB, qC; float sB, zB, sC, zC;
  {
    int4 qA; float sA, zA;
    load_q(0, qA, sA, zA);        // 3 vm
    stage_x(0, 0);                // 4 vm (glds step 0)
    SCHED0();
    load_q(1, qB, sB, zB);        // 3 vm
    dequant_write(qA, sA, zA, 0); // compiler waits qA
  }
  ASM_LGKM_0(); SBAR();

  // ---- uniform pipelined loop: t = 0..61 ----
  int b = 0;
  #pragma unroll 1
  for (int t = 0; t <= 61; ++t) {
    stage_x(b ^ 1, t + 1);        // 4 glds (pinned before q loads)
    SCHED0();
    load_q(t + 2, qC, sC, zC);    // 3 vm, depth-2 prefetch
    ASM_VMCNT_10(); SCHED0();     // glds(t) done: 3(qB')+4(glds t+1)+3(qC)=10 newer
    compute(b);                   // ds_read + 8 MFMA (wave-private x rows)
    dequant_write(qB, sB, zB, b ^ 1);
    ASM_LGKM_0(); SBAR();         // wt[b^1] visible to all waves next step
    qB = qC; sB = sC; zB = zC;
    b ^= 1;
  }

  // ---- t = 62 ----
  stage_x(b ^ 1, 63);             // 4 glds
  ASM_VMCNT_7(); SCHED0();        // glds(62): 3(q63)+4(glds63)=7 newer
  compute(b);
  dequant_write(qB, sB, zB, b ^ 1);   // step 63 weights
  ASM_LGKM_0(); SBAR();
  b ^= 1;

  // ---- t = 63 (+ stage lora step 64) ----
  stage_x(b ^ 1, 64);             // 4 glds (x_ext cols 4096..4159)
  SCHED0();
  int4 qL = {0, 0, 0, 0};
  if (lora_ld) qL = *(const int4*)(lb + (size_t)nglob * 16 + sko);   // 1 vm
  ASM_VMCNT_5(); SCHED0();        // glds(63): 4(glds64)+1(qL)=5 newer
  compute(b);
  {
    unsigned short wv0 = lora_ld ? f2bf(__int_as_float(qL.x)) : (unsigned short)0;
    unsigned short wv1 = lora_ld ? f2bf(__int_as_float(qL.y)) : (unsigned short)0;
    unsigned short wv2 = lora_ld ? f2bf(__int_as_float(qL.z)) : (unsigned short)0;
    unsigned short wv3 = lora_ld ? f2bf(__int_as_float(qL.w)) : (unsigned short)0;
    int2 pk;
    pk.x = (int)wv0 | ((int)wv1 << 16);
    pk.y = (int)wv2 | ((int)wv3 << 16);
    *(int2*)((char*)wt[b ^ 1] + wt_off) = pk;
  }
  ASM_LGKM_0(); SBAR();
  b ^= 1;

  // ---- t = 64 (lora columns) ----
  ASM_VMCNT_0(); SCHED0();
  compute(b);

  // ---- epilogue: C/D layout col=lane&15, row=(lane>>4)*4+reg ----
  const int rb = wave * 32 + (lane >> 4) * 4;
  const int cb = n0 + (lane & 15);
  #pragma unroll
  for (int mf = 0; mf < 2; ++mf) {
    #pragma unroll
    for (int nf = 0; nf < 2; ++nf) {
      #pragma unroll
      for (int j = 0; j < 4; ++j) {
        out[(size_t)(rb + mf * 16 + j) * N_OUT + (cb + nf * 16)] = acc[mf][nf][j];
      }
    }
  }
}

extern "C" void kernel_launch(void* const* d_in, const int* in_sizes, int n_in,
                              void* d_out, int out_size, void* d_ws, size_t ws_size,
                              hipStream_t stream) {
  const float* x  = (const float*)d_in[0];
  const int*   qw = (const int*)d_in[1];
  const float* sc = (const float*)d_in[2];
  const int*   zr = (const int*)d_in[3];
  const float* la = (const float*)d_in[4];
  const float* lb = (const float*)d_in[5];
  float* out = (float*)d_out;
  unsigned short* xe = (unsigned short*)d_ws;   // 256*4160*2 = 2.03 MB

  prep_kernel<<<M_TOK, 512, 0, stream>>>(x, la, xe);
  gptq_lora_gemm<<<NBLK, 512, 0, stream>>>(qw, sc, zr, lb, xe, out);
}